// Round 5
// baseline (441.561 us; speedup 1.0000x reference)
//
#include <hip/hip_runtime.h>
#include <hip/hip_bf16.h>
#include <hip/hip_cooperative_groups.h>

namespace cg = cooperative_groups;

typedef __attribute__((ext_vector_type(4))) float f32x4;
typedef __attribute__((ext_vector_type(8))) short short8;

#define LN2F 0.69314718055994531f

__device__ __forceinline__ unsigned short f2b(float x){
  union{float f;unsigned u;}v; v.f=x;
  unsigned r = v.u + 0x7fffu + ((v.u>>16)&1u);
  return (unsigned short)(r>>16);
}
__device__ __forceinline__ float b2f(unsigned short h){
  union{unsigned u;float f;}v; v.u = ((unsigned)h)<<16; return v.f;
}
__device__ __forceinline__ float sigm(float x){ return 1.f/(1.f+__expf(-x)); }
__device__ __forceinline__ float tanh_(float x){ float t=__expf(2.f*x); return 1.f - 2.f/(t+1.f); }

// ---------------- prep: gathers + f32->bf16 conversions + E table + Y out ----
__global__ __launch_bounds__(256) void prep_kernel(
  const int* __restrict__ X, const int* __restrict__ Y,
  const float* __restrict__ h0, const float* __restrict__ c0,
  const float* __restrict__ emb,
  const float* __restrict__ WihF, const float* __restrict__ WihB,
  const float* __restrict__ WhhFf, const float* __restrict__ WhhBf,
  const float* __restrict__ fcWf, const float* __restrict__ trans,
  unsigned short* __restrict__ Abf, unsigned short* __restrict__ Wcat,
  unsigned short* __restrict__ WhhF, unsigned short* __restrict__ WhhB,
  unsigned short* __restrict__ hbufs, float* __restrict__ cbuf,
  unsigned short* __restrict__ fcW, unsigned short* __restrict__ Ebf,
  float* __restrict__ out)
{
  const int tid = blockIdx.x*256 + threadIdx.x;
  const int nth = gridDim.x*256;
  for(int i=tid;i<524288;i+=nth){
    int r = i>>7, q = i&127;
    float4 v = ((const float4*)(emb + (size_t)X[r]*512))[q];
    ushort4 o; o.x=f2b(v.x); o.y=f2b(v.y); o.z=f2b(v.z); o.w=f2b(v.w);
    ((ushort4*)Abf)[i] = o;
  }
  for(int i=tid;i<524288;i+=nth){
    int r = i>>7, q = i&127;
    const float* src = (r<2048) ? (WihF + (size_t)r*512) : (WihB + (size_t)(r-2048)*512);
    float4 v = ((const float4*)src)[q];
    ushort4 o; o.x=f2b(v.x); o.y=f2b(v.y); o.z=f2b(v.z); o.w=f2b(v.w);
    ((ushort4*)Wcat)[i] = o;
  }
  for(int i=tid;i<262144;i+=nth){
    float4 v = ((const float4*)WhhFf)[i];
    ushort4 o; o.x=f2b(v.x); o.y=f2b(v.y); o.z=f2b(v.z); o.w=f2b(v.w);
    ((ushort4*)WhhF)[i] = o;
  }
  for(int i=tid;i<262144;i+=nth){
    float4 v = ((const float4*)WhhBf)[i];
    ushort4 o; o.x=f2b(v.x); o.y=f2b(v.y); o.z=f2b(v.z); o.w=f2b(v.w);
    ((ushort4*)WhhB)[i] = o;
  }
  for(int i=tid;i<131072;i+=nth){
    int d = i>>16, rest = i&65535;
    float4 v = ((const float4*)h0)[i];
    ushort4 o; o.x=f2b(v.x); o.y=f2b(v.y); o.z=f2b(v.z); o.w=f2b(v.w);
    ((ushort4*)hbufs)[(size_t)(d*2)*65536 + rest] = o;
  }
  for(int i=tid;i<131072;i+=nth) ((float4*)cbuf)[i] = ((const float4*)c0)[i];
  for(int i=tid;i<16384;i+=nth){
    int n = i>>8, q = i&255;
    float4 v;
    if (n<50) v = ((const float4*)(fcWf + (size_t)n*1024))[q];
    else { v.x=0.f; v.y=0.f; v.z=0.f; v.w=0.f; }
    ushort4 o; o.x=f2b(v.x); o.y=f2b(v.y); o.z=f2b(v.z); o.w=f2b(v.w);
    ((ushort4*)fcW)[i] = o;
  }
  // Ebf[n][p] = exp(trans[n][p]) bf16, padded [64][64]
  for(int i=tid;i<4096;i+=nth){
    int n = i>>6, p = i&63;
    float v = (n<50 && p<50) ? __expf(trans[n*50+p]) : 0.f;
    Ebf[i] = f2b(v);
  }
  for(int i=tid;i<4096;i+=nth) out[1+i] = (float)Y[i];
}

// ---------------- GEMM1: Gin = A @ Wcat^T, all bf16, C stored bf16 ----------
__global__ __launch_bounds__(256) void gemm1_kernel(const unsigned short* __restrict__ A,
                                                    const unsigned short* __restrict__ B,
                                                    unsigned short* __restrict__ C){
  __shared__ __align__(16) unsigned short As[128*40];
  __shared__ __align__(16) unsigned short Bs[128*40];
  const int t = threadIdx.x, w = t>>6, l = t&63;
  const int m0 = blockIdx.x<<7, n0 = blockIdx.y<<7;
  const int wr = (w>>1)<<6, wc = (w&1)<<6;
  const int srow = t>>2, scol = (t&3)<<3;
  const int fr = l&15, fk = (l>>4)<<3;
  f32x4 acc[4][4];
  #pragma unroll
  for(int i=0;i<4;i++)
    #pragma unroll
    for(int j=0;j<4;j++) acc[i][j]=(f32x4)0.f;
  const unsigned short* Ab = A + (size_t)m0*512;
  const unsigned short* Bb = B + (size_t)n0*512;
  uint4 pa0 = *(const uint4*)(Ab + srow*512 + scol);
  uint4 pa1 = *(const uint4*)(Ab + (64+srow)*512 + scol);
  uint4 pb0 = *(const uint4*)(Bb + srow*512 + scol);
  uint4 pb1 = *(const uint4*)(Bb + (64+srow)*512 + scol);
  for(int kt=0; kt<16; ++kt){
    __syncthreads();
    *(uint4*)&As[srow*40 + scol] = pa0;
    *(uint4*)&As[(64+srow)*40 + scol] = pa1;
    *(uint4*)&Bs[srow*40 + scol] = pb0;
    *(uint4*)&Bs[(64+srow)*40 + scol] = pb1;
    __syncthreads();
    if (kt<15){
      int kc = (kt+1)*32 + scol;
      pa0 = *(const uint4*)(Ab + srow*512 + kc);
      pa1 = *(const uint4*)(Ab + (64+srow)*512 + kc);
      pb0 = *(const uint4*)(Bb + srow*512 + kc);
      pb1 = *(const uint4*)(Bb + (64+srow)*512 + kc);
    }
    short8 af[4], bf[4];
    #pragma unroll
    for(int mi=0;mi<4;mi++) af[mi] = *(const short8*)&As[(wr+mi*16+fr)*40 + fk];
    #pragma unroll
    for(int ni=0;ni<4;ni++) bf[ni] = *(const short8*)&Bs[(wc+ni*16+fr)*40 + fk];
    #pragma unroll
    for(int mi=0;mi<4;mi++)
      #pragma unroll
      for(int ni=0;ni<4;ni++)
        acc[mi][ni] = __builtin_amdgcn_mfma_f32_16x16x32_bf16(af[mi], bf[ni], acc[mi][ni], 0,0,0);
  }
  #pragma unroll
  for(int mi=0;mi<4;mi++)
    #pragma unroll
    for(int ni=0;ni<4;ni++)
      #pragma unroll
      for(int j=0;j<4;j++){
        int row = m0 + wr + mi*16 + ((l>>4)<<2) + j;
        int col = n0 + wc + ni*16 + fr;
        C[(size_t)row*4096 + col] = f2b(acc[mi][ni][j]);
      }
}

// ------- cooperative LSTM: all 8 steps, W resident in LDS, A from global ----
// grid = 256 blocks (1/CU): bid = d*128 + chunk*32 + ublock
__global__ __launch_bounds__(256, 1) void lstm_coop_kernel(
  unsigned short* __restrict__ hbufs, float* __restrict__ cbuf,
  unsigned short* __restrict__ hall, const unsigned short* __restrict__ Gin,
  const unsigned short* __restrict__ WhhF_, const unsigned short* __restrict__ WhhB_,
  const float* __restrict__ bF, const float* __restrict__ bB)
{
  __shared__ __align__(16) unsigned short WL[16*64*32];  // [kt][g][lane(q*16+ul)][8] = 64 KB
  cg::grid_group grid = cg::this_grid();
  const int bid = blockIdx.x;
  const int d  = bid >> 7;
  const int m0 = ((bid >> 5) & 3) << 7;
  const int u0 = (bid & 31) << 4;
  const unsigned short* W = d ? WhhB_ : WhhF_;
  const float* bias = d ? bB : bF;
  const int tx = threadIdx.x, w = tx>>6, l = tx&63;
  const int fr = l&15, q = l>>4;
  // one-time W load: thread t covers (row = t>>2 = g*16+ul, qq = t&3) per k-tile
  {
    const int row = tx >> 2, qq = tx & 3;
    const int g = row >> 4, ul = row & 15;
    const int grow = (g<<9) + u0 + ul;
    #pragma unroll
    for(int kt=0;kt<16;kt++){
      uint4 v = *(const uint4*)(W + (size_t)grow*512 + kt*32 + qq*8);
      *(uint4*)((char*)WL + (((kt*4 + g)*64) + (qq*16 + ul))*16) = v;
    }
  }
  __syncthreads();
  for(int t=0;t<8;t++){
    const int tin = d ? (7-t) : t;
    const int par = t&1;
    const unsigned short* hprev = hbufs + (size_t)(d*2+par)*262144;
    unsigned short* hnext = hbufs + (size_t)(d*2+(par^1))*262144;
    f32x4 acc[2][4];
    #pragma unroll
    for(int i=0;i<2;i++)
      #pragma unroll
      for(int j=0;j<4;j++) acc[i][j]=(f32x4)0.f;
    const unsigned short* arow0 = hprev + (size_t)(m0 + w*32 + fr)*512 + q*8;
    const unsigned short* arow1 = arow0 + (size_t)16*512;
    uint4 af0 = *(const uint4*)arow0;
    uint4 af1 = *(const uint4*)arow1;
    for(int kt=0; kt<16; ++kt){
      uint4 nf0 = af0, nf1 = af1;
      if(kt<15){
        nf0 = *(const uint4*)(arow0 + (kt+1)*32);
        nf1 = *(const uint4*)(arow1 + (kt+1)*32);
      }
      short8 a0 = __builtin_bit_cast(short8, af0);
      short8 a1 = __builtin_bit_cast(short8, af1);
      short8 bf[4];
      #pragma unroll
      for(int g=0;g<4;g++)
        bf[g] = *(const short8*)((char*)WL + (((kt*4 + g)*64) + l)*16);
      #pragma unroll
      for(int g=0;g<4;g++){
        acc[0][g] = __builtin_amdgcn_mfma_f32_16x16x32_bf16(a0, bf[g], acc[0][g], 0,0,0);
        acc[1][g] = __builtin_amdgcn_mfma_f32_16x16x32_bf16(a1, bf[g], acc[1][g], 0,0,0);
      }
      af0 = nf0; af1 = nf1;
    }
    #pragma unroll
    for(int mi=0;mi<2;mi++)
      #pragma unroll
      for(int j=0;j<4;j++){
        int rs = m0 + w*32 + mi*16 + (q<<2) + j;
        int u  = u0 + fr;
        size_t grow = (size_t)(tin*512 + rs)*4096 + (size_t)d*2048;
        float p0 = acc[mi][0][j] + b2f(Gin[grow +    0 + u]) + bias[   0+u];
        float p1 = acc[mi][1][j] + b2f(Gin[grow +  512 + u]) + bias[ 512+u];
        float p2 = acc[mi][2][j] + b2f(Gin[grow + 1024 + u]) + bias[1024+u];
        float p3 = acc[mi][3][j] + b2f(Gin[grow + 1536 + u]) + bias[1536+u];
        size_t ci = (size_t)d*262144 + (size_t)rs*512 + u;
        float c = sigm(p1)*cbuf[ci] + sigm(p0)*tanh_(p2);
        cbuf[ci] = c;
        float h = sigm(p3)*tanh_(c);
        hnext[(size_t)rs*512+u] = f2b(h);
        hall[(size_t)(tin*512+rs)*1024 + (size_t)d*512 + u] = f2b(h);
      }
    if(t<7) grid.sync();
  }
}

// ---------------- fc: feats = h_all @ fcW^T + b  -> f32 [4096][64] (padded) --
__global__ __launch_bounds__(256) void fc_kernel(const unsigned short* __restrict__ hA,
    const unsigned short* __restrict__ Wf, const float* __restrict__ fcb,
    float* __restrict__ feats){
  __shared__ __align__(16) unsigned short As[128*40];
  __shared__ __align__(16) unsigned short Bs[64*40];
  const int tx = threadIdx.x, w = tx>>6, l = tx&63;
  const int m0 = blockIdx.x<<7;
  const int srow = tx>>2, scol = (tx&3)<<3;
  const int fr=l&15, fk=(l>>4)<<3;
  f32x4 acc[2][4];
  #pragma unroll
  for(int i=0;i<2;i++)
    #pragma unroll
    for(int j=0;j<4;j++) acc[i][j]=(f32x4)0.f;
  uint4 pa0 = *(const uint4*)(hA + (size_t)(m0+srow)*1024 + scol);
  uint4 pa1 = *(const uint4*)(hA + (size_t)(m0+64+srow)*1024 + scol);
  uint4 pb0 = *(const uint4*)(Wf + (size_t)srow*1024 + scol);
  for(int kt=0; kt<32; ++kt){
    __syncthreads();
    *(uint4*)&As[srow*40+scol] = pa0;
    *(uint4*)&As[(64+srow)*40+scol] = pa1;
    *(uint4*)&Bs[srow*40+scol] = pb0;
    __syncthreads();
    if(kt<31){
      int kc = (kt+1)*32 + scol;
      pa0 = *(const uint4*)(hA + (size_t)(m0+srow)*1024 + kc);
      pa1 = *(const uint4*)(hA + (size_t)(m0+64+srow)*1024 + kc);
      pb0 = *(const uint4*)(Wf + (size_t)srow*1024 + kc);
    }
    short8 af[2], bf[4];
    #pragma unroll
    for(int mi=0;mi<2;mi++) af[mi] = *(const short8*)&As[(w*32+mi*16+fr)*40 + fk];
    #pragma unroll
    for(int ni=0;ni<4;ni++) bf[ni] = *(const short8*)&Bs[(ni*16+fr)*40 + fk];
    #pragma unroll
    for(int mi=0;mi<2;mi++)
      #pragma unroll
      for(int ni=0;ni<4;ni++)
        acc[mi][ni] = __builtin_amdgcn_mfma_f32_16x16x32_bf16(af[mi], bf[ni], acc[mi][ni], 0,0,0);
  }
  #pragma unroll
  for(int mi=0;mi<2;mi++)
    #pragma unroll
    for(int ni=0;ni<4;ni++)
      #pragma unroll
      for(int j=0;j<4;j++){
        int rs = m0 + w*32 + mi*16 + ((l>>4)<<2) + j;
        int n  = ni*16 + fr;
        feats[(size_t)rs*64+n] = acc[mi][ni][j] + (n<50 ? fcb[n] : 0.f);
      }
}

// ---- CRF level 1: product of 16 transition-step matrices per block ---------
__global__ __launch_bounds__(64) void crf_group_kernel(
    const float* __restrict__ feats, const unsigned short* __restrict__ Ebf,
    float* __restrict__ Wout, int* __restrict__ kexp)
{
  __shared__ __align__(16) unsigned short PT[64*72];
  __shared__ float fe[16*64];
  const int g = blockIdx.x, b = blockIdx.y;
  const int l = threadIdx.x;
  const int lj = l & 15, q = l >> 4;
  const float* fb = feats + (size_t)(b*512 + g*16)*64;
  #pragma unroll
  for(int j=0;j<16;j++) fe[j*64 + l] = fb[j*64 + l];
  short8 afE[4][2];
  #pragma unroll
  for(int i=0;i<4;i++)
    #pragma unroll
    for(int h=0;h<2;h++)
      afE[i][h] = *(const short8*)(Ebf + (i*16+lj)*64 + h*32 + q*8);
  {
    uint4 erow[8];
    #pragma unroll
    for(int i=0;i<8;i++) erow[i] = *(const uint4*)(Ebf + l*64 + i*8);
    float ef0 = __expf(fe[l]);
    const unsigned* e32 = (const unsigned*)erow;
    #pragma unroll
    for(int m=0;m<64;m++){
      unsigned short eb = (unsigned short)(e32[m>>1] >> ((m&1)*16));
      PT[m*72 + l] = f2b(b2f(eb) * ef0);
    }
  }
  float sc_lag = 1.f;
  int exprev = 0, kblk = 0;
  #pragma unroll
  for(int k=1;k<16;k++){
    kblk += exprev;
    float ev[4][4];
    #pragma unroll
    for(int i=0;i<4;i++)
      #pragma unroll
      for(int r=0;r<4;r++)
        ev[i][r] = __expf(fe[k*64 + i*16 + q*4 + r]) * sc_lag;
    short8 bfP[4][2];
    #pragma unroll
    for(int j=0;j<4;j++)
      #pragma unroll
      for(int h=0;h<2;h++)
        bfP[j][h] = *(const short8*)&PT[(j*16+lj)*72 + h*32 + q*8];
    f32x4 acc[4][4];
    #pragma unroll
    for(int i=0;i<4;i++)
      #pragma unroll
      for(int j=0;j<4;j++) acc[i][j] = (f32x4)0.f;
    #pragma unroll
    for(int h=0;h<2;h++)
      #pragma unroll
      for(int i=0;i<4;i++)
        #pragma unroll
        for(int j=0;j<4;j++)
          acc[i][j] = __builtin_amdgcn_mfma_f32_16x16x32_bf16(afE[i][h], bfP[j][h], acc[i][j], 0,0,0);
    float mx = 1e-30f;
    float* Wo = Wout + (size_t)(b*32 + g)*4096;
    #pragma unroll
    for(int i=0;i<4;i++)
      #pragma unroll
      for(int j=0;j<4;j++){
        float v0 = acc[i][j][0]*ev[i][0];
        float v1 = acc[i][j][1]*ev[i][1];
        float v2 = acc[i][j][2]*ev[i][2];
        float v3 = acc[i][j][3]*ev[i][3];
        mx = fmaxf(fmaxf(mx, fmaxf(v0,v1)), fmaxf(v2,v3));
        int base = (j*16+lj)*72 + i*16 + q*4;
        *(unsigned*)&PT[base]   = (unsigned)f2b(v0) | ((unsigned)f2b(v1)<<16);
        *(unsigned*)&PT[base+2] = (unsigned)f2b(v2) | ((unsigned)f2b(v3)<<16);
        if(k==15){
          int n = i*16 + q*4, m = j*16 + lj;
          Wo[(size_t)(n+0)*64 + m] = v0;
          Wo[(size_t)(n+1)*64 + m] = v1;
          Wo[(size_t)(n+2)*64 + m] = v2;
          Wo[(size_t)(n+3)*64 + m] = v3;
        }
      }
    #pragma unroll
    for(int off=1; off<64; off<<=1) mx = fmaxf(mx, __shfl_xor(mx, off));
    int ex = ((__builtin_bit_cast(int, mx) >> 23) & 0xff) - 127;
    ex = ex < -120 ? -120 : (ex > 120 ? 120 : ex);
    sc_lag = __builtin_bit_cast(float, (unsigned)((127-ex)<<23));
    exprev = ex;
  }
  if(l==0) kexp[b*32 + g] = kblk;
}

// ---- CRF level 2: sequential over 32 group matrices, pure f32 matvec -------
__global__ __launch_bounds__(64) void crf_seq_kernel(const float* __restrict__ W,
    const int* __restrict__ kexp, const float* __restrict__ trans,
    float* __restrict__ scores){
  __shared__ __align__(16) float sh[64];
  const int b = blockIdx.x, l = threadIdx.x;
  const float* Wb = W + (size_t)b*131072;
  float kl = (l<32) ? (float)kexp[b*32 + l] : 0.f;
  #pragma unroll
  for(int off=32;off;off>>=1) kl += __shfl_down(kl, off);
  float G = (l==48) ? 1.f : 0.f;
  float sc = 1.f, Mrun = 0.f;
  int exprev = 0;
  float4 curA[16], curB[16];
  #pragma unroll
  for(int i=0;i<16;i++) curA[i] = ((const float4*)(Wb + (size_t)l*64))[i];

#define SEQ_STEP(CUR, NXT, GI) {                                            \
    sh[l] = G;                                                              \
    const float* wn = Wb + (size_t)(((GI)+1)&31)*4096 + (size_t)l*64;       \
    _Pragma("unroll")                                                       \
    for(int i=0;i<16;i++) NXT[i] = ((const float4*)wn)[i];                  \
    float4 gq[16];                                                          \
    _Pragma("unroll")                                                       \
    for(int i=0;i<16;i++) gq[i] = ((const float4*)sh)[i];                   \
    float a0=0.f,a1=0.f,a2=0.f,a3=0.f;                                      \
    _Pragma("unroll")                                                       \
    for(int i=0;i<16;i++){                                                  \
      a0 = fmaf(CUR[i].x, gq[i].x, a0);                                     \
      a1 = fmaf(CUR[i].y, gq[i].y, a1);                                     \
      a2 = fmaf(CUR[i].z, gq[i].z, a2);                                     \
      a3 = fmaf(CUR[i].w, gq[i].w, a3);                                     \
    }                                                                       \
    float S = (a0+a1)+(a2+a3);                                              \
    Mrun += (float)exprev;                                                  \
    G = S * sc;                                                             \
    float Sp = __builtin_bit_cast(float, __builtin_amdgcn_readfirstlane(    \
                 __builtin_bit_cast(int, fmaxf(S, 1e-35f))));               \
    int ex = ((__builtin_bit_cast(int, Sp) >> 23) & 0xff) - 127;            \
    ex = ex < -120 ? -120 : (ex > 120 ? 120 : ex);                          \
    sc = __builtin_bit_cast(float, (unsigned)((127-ex)<<23));               \
    exprev = ex;                                                            \
  }

  for(int g=0; g<32; g+=2){
    SEQ_STEP(curA, curB, g)
    SEQ_STEP(curB, curA, g+1)
  }
#undef SEQ_STEP
  float u = (l<50) ? __expf(trans[49*50+l]) : 0.f;
  float val = G * u;
  #pragma unroll
  for(int off=32;off;off>>=1) val += __shfl_down(val, off);
  if(l==0) scores[b] = logf(fmaxf(val,1e-35f)) + (Mrun + kl)*LN2F;
}

// ---------------- gold score + final combine --------------------------------
__global__ __launch_bounds__(256) void final_kernel(const int* __restrict__ Y,
   const float* __restrict__ trans, const float* __restrict__ feats,
   const float* __restrict__ scores, float* __restrict__ out){
  const int tx = threadIdx.x;
  float acc = 0.f;
  for(int i=tx; i<4096; i+=256){
    int s = i & 511;
    int y = Y[i];
    int prev = s ? Y[i-1] : 48;
    acc += trans[y*50+prev] + feats[(size_t)i*64+y];
    if (s==511) acc += trans[49*50+y];
  }
  #pragma unroll
  for(int off=32; off; off>>=1) acc += __shfl_down(acc, off);
  __shared__ float red[4];
  if((tx&63)==0) red[tx>>6] = acc;
  __syncthreads();
  if(tx==0){
    float gold = red[0]+red[1]+red[2]+red[3];
    float fwd = 0.f;
    #pragma unroll
    for(int b=0;b<8;b++) fwd += scores[b];
    out[0] = fwd - gold;
  }
}

extern "C" void kernel_launch(void* const* d_in, const int* in_sizes, int n_in,
                              void* d_out, int out_size, void* d_ws, size_t ws_size,
                              hipStream_t stream) {
  (void)in_sizes; (void)n_in; (void)out_size; (void)ws_size;
  const int*   X     = (const int*)d_in[0];
  const int*   Y     = (const int*)d_in[1];
  const float* h0    = (const float*)d_in[2];
  const float* c0    = (const float*)d_in[3];
  const float* emb   = (const float*)d_in[4];
  const float* WihF  = (const float*)d_in[5];
  const float* WhhFf = (const float*)d_in[6];
  const float* bF    = (const float*)d_in[7];
  const float* WihB  = (const float*)d_in[8];
  const float* WhhBf = (const float*)d_in[9];
  const float* bB    = (const float*)d_in[10];
  const float* fcWf  = (const float*)d_in[11];
  const float* fcb   = (const float*)d_in[12];
  const float* trans = (const float*)d_in[13];
  float* out = (float*)d_out;
  char* ws = (char*)d_ws;

  unsigned short* Abf   = (unsigned short*)(ws + 0);
  unsigned short* Wcat  = (unsigned short*)(ws + 4194304);
  unsigned short* WhhF  = (unsigned short*)(ws + 8388608);
  unsigned short* WhhB  = (unsigned short*)(ws + 10485760);
  unsigned short* Gin   = (unsigned short*)(ws + 12582912);   // 32 MB, reused after lstm
  float*          Wgrp  = (float*)(ws + 12582912);            // overlays Gin: 8*32*4096 f32 = 4 MB
  int*            kexp  = (int*)(ws + 20971520);
  unsigned short* hbufs = (unsigned short*)(ws + 46137344);
  float*          cbuf  = (float*)(ws + 48234496);
  unsigned short* hall  = (unsigned short*)(ws + 50331648);
  unsigned short* fcW   = (unsigned short*)(ws + 58720256);
  float*          feats = (float*)(ws + 58851328);            // 4096*64 f32 + pad
  unsigned short* Ebf   = (unsigned short*)(ws + 59900160);
  float*          scores= (float*)(ws + 59913472);

  hipLaunchKernelGGL(prep_kernel, dim3(1024), dim3(256), 0, stream,
      X, Y, h0, c0, emb, WihF, WihB, WhhFf, WhhBf, fcWf, trans,
      Abf, Wcat, WhhF, WhhB, hbufs, cbuf, fcW, Ebf, out);
  hipLaunchKernelGGL(gemm1_kernel, dim3(32,32), dim3(256), 0, stream, Abf, Wcat, Gin);
  {
    const unsigned short* GinC = Gin;
    const unsigned short* WhhFc = WhhF;
    const unsigned short* WhhBc = WhhB;
    void* args[] = { (void*)&hbufs, (void*)&cbuf, (void*)&hall, (void*)&GinC,
                     (void*)&WhhFc, (void*)&WhhBc, (void*)&bF, (void*)&bB };
    hipLaunchCooperativeKernel((const void*)lstm_coop_kernel, dim3(256), dim3(256),
                               args, 0, stream);
  }
  hipLaunchKernelGGL(fc_kernel, dim3(32), dim3(256), 0, stream, hall, fcW, fcb, feats);
  hipLaunchKernelGGL(crf_group_kernel, dim3(32,8), dim3(64), 0, stream, feats, Ebf, Wgrp, kexp);
  hipLaunchKernelGGL(crf_seq_kernel, dim3(8), dim3(64), 0, stream, Wgrp, kexp, trans, scores);
  hipLaunchKernelGGL(final_kernel, dim3(1), dim3(256), 0, stream, Y, trans, feats, scores, out);
}

// Round 6
// 209.674 us; speedup vs baseline: 2.1059x; 2.1059x over previous
//
#include <hip/hip_runtime.h>
#include <hip/hip_bf16.h>

typedef __attribute__((ext_vector_type(4))) float f32x4;
typedef __attribute__((ext_vector_type(8))) short short8;

#define LN2F 0.69314718055994531f

__device__ __forceinline__ unsigned short f2b(float x){
  union{float f;unsigned u;}v; v.f=x;
  unsigned r = v.u + 0x7fffu + ((v.u>>16)&1u);
  return (unsigned short)(r>>16);
}
__device__ __forceinline__ float b2f(unsigned short h){
  union{unsigned u;float f;}v; v.u = ((unsigned)h)<<16; return v.f;
}
__device__ __forceinline__ float sigm(float x){ return 1.f/(1.f+__expf(-x)); }
__device__ __forceinline__ float tanh_(float x){ float t=__expf(2.f*x); return 1.f - 2.f/(t+1.f); }

// async global->LDS, 16B per lane; LDS dest = wave-uniform base + lane*16
__device__ __forceinline__ void gll16(const void* g, void* l){
  __builtin_amdgcn_global_load_lds((const __attribute__((address_space(1))) void*)g,
                                   (__attribute__((address_space(3))) void*)l, 16, 0, 0);
}

// ---------------- prep: gathers + f32->bf16 conversions + E table + Y out ----
__global__ __launch_bounds__(256) void prep_kernel(
  const int* __restrict__ X, const int* __restrict__ Y,
  const float* __restrict__ h0, const float* __restrict__ c0,
  const float* __restrict__ emb,
  const float* __restrict__ WihF, const float* __restrict__ WihB,
  const float* __restrict__ WhhFf, const float* __restrict__ WhhBf,
  const float* __restrict__ fcWf, const float* __restrict__ trans,
  unsigned short* __restrict__ Abf, unsigned short* __restrict__ Wcat,
  unsigned short* __restrict__ WhhF, unsigned short* __restrict__ WhhB,
  unsigned short* __restrict__ hbufs, float* __restrict__ cbuf,
  unsigned short* __restrict__ fcW, unsigned short* __restrict__ Ebf,
  float* __restrict__ out)
{
  const int tid = blockIdx.x*256 + threadIdx.x;
  const int nth = gridDim.x*256;
  for(int i=tid;i<524288;i+=nth){
    int r = i>>7, q = i&127;
    float4 v = ((const float4*)(emb + (size_t)X[r]*512))[q];
    ushort4 o; o.x=f2b(v.x); o.y=f2b(v.y); o.z=f2b(v.z); o.w=f2b(v.w);
    ((ushort4*)Abf)[i] = o;
  }
  for(int i=tid;i<524288;i+=nth){
    int r = i>>7, q = i&127;
    const float* src = (r<2048) ? (WihF + (size_t)r*512) : (WihB + (size_t)(r-2048)*512);
    float4 v = ((const float4*)src)[q];
    ushort4 o; o.x=f2b(v.x); o.y=f2b(v.y); o.z=f2b(v.z); o.w=f2b(v.w);
    ((ushort4*)Wcat)[i] = o;
  }
  for(int i=tid;i<262144;i+=nth){
    float4 v = ((const float4*)WhhFf)[i];
    ushort4 o; o.x=f2b(v.x); o.y=f2b(v.y); o.z=f2b(v.z); o.w=f2b(v.w);
    ((ushort4*)WhhF)[i] = o;
  }
  for(int i=tid;i<262144;i+=nth){
    float4 v = ((const float4*)WhhBf)[i];
    ushort4 o; o.x=f2b(v.x); o.y=f2b(v.y); o.z=f2b(v.z); o.w=f2b(v.w);
    ((ushort4*)WhhB)[i] = o;
  }
  for(int i=tid;i<131072;i+=nth){
    int d = i>>16, rest = i&65535;
    float4 v = ((const float4*)h0)[i];
    ushort4 o; o.x=f2b(v.x); o.y=f2b(v.y); o.z=f2b(v.z); o.w=f2b(v.w);
    ((ushort4*)hbufs)[(size_t)(d*2)*65536 + rest] = o;
  }
  for(int i=tid;i<131072;i+=nth) ((float4*)cbuf)[i] = ((const float4*)c0)[i];
  for(int i=tid;i<16384;i+=nth){
    int n = i>>8, q = i&255;
    float4 v;
    if (n<50) v = ((const float4*)(fcWf + (size_t)n*1024))[q];
    else { v.x=0.f; v.y=0.f; v.z=0.f; v.w=0.f; }
    ushort4 o; o.x=f2b(v.x); o.y=f2b(v.y); o.z=f2b(v.z); o.w=f2b(v.w);
    ((ushort4*)fcW)[i] = o;
  }
  // Ebf[n][p] = exp(trans[n][p]) bf16, padded [64][64]
  for(int i=tid;i<4096;i+=nth){
    int n = i>>6, p = i&63;
    float v = (n<50 && p<50) ? __expf(trans[n*50+p]) : 0.f;
    Ebf[i] = f2b(v);
  }
  for(int i=tid;i<4096;i+=nth) out[1+i] = (float)Y[i];
}

// ---------------- GEMM1: Gin = A @ Wcat^T (m97-style global_load_lds) -------
__global__ __launch_bounds__(256) void gemm1_kernel(const unsigned short* __restrict__ A,
                                                    const unsigned short* __restrict__ B,
                                                    unsigned short* __restrict__ C){
  __shared__ __align__(16) unsigned short As[128*32];
  __shared__ __align__(16) unsigned short Bs[128*32];
  const int t = threadIdx.x, w = t>>6, l = t&63;
  const int m0 = blockIdx.x<<7, n0 = blockIdx.y<<7;
  const int wr = (w>>1)<<6, wc = (w&1)<<6;
  const int fr = l&15, fk = (l>>4)<<3;
  f32x4 acc[4][4];
  #pragma unroll
  for(int i=0;i<4;i++)
    #pragma unroll
    for(int j=0;j<4;j++) acc[i][j]=(f32x4)0.f;
  const unsigned short* Ab = A + (size_t)m0*512;
  const unsigned short* Bb = B + (size_t)n0*512;
  const int r0 = (w<<5) + (l>>2);       // wave w stages rows w*32..w*32+31 (2 segs)
  const int c0 = (l&3)<<3;
  unsigned short* asd = As + (w<<5)*32;
  unsigned short* bsd = Bs + (w<<5)*32;
  for(int kt=0; kt<16; ++kt){
    __syncthreads();
    const int kc = (kt<<5) + c0;
    gll16(Ab + (size_t)r0*512 + kc,      asd);
    gll16(Ab + (size_t)(r0+16)*512 + kc, asd + 16*32);
    gll16(Bb + (size_t)r0*512 + kc,      bsd);
    gll16(Bb + (size_t)(r0+16)*512 + kc, bsd + 16*32);
    asm volatile("s_waitcnt vmcnt(0)" ::: "memory");
    __syncthreads();
    short8 af[4], bf[4];
    #pragma unroll
    for(int mi=0;mi<4;mi++) af[mi] = *(const short8*)&As[(wr+mi*16+fr)*32 + fk];
    #pragma unroll
    for(int ni=0;ni<4;ni++) bf[ni] = *(const short8*)&Bs[(wc+ni*16+fr)*32 + fk];
    #pragma unroll
    for(int mi=0;mi<4;mi++)
      #pragma unroll
      for(int ni=0;ni<4;ni++)
        acc[mi][ni] = __builtin_amdgcn_mfma_f32_16x16x32_bf16(af[mi], bf[ni], acc[mi][ni], 0,0,0);
  }
  #pragma unroll
  for(int mi=0;mi<4;mi++)
    #pragma unroll
    for(int ni=0;ni<4;ni++)
      #pragma unroll
      for(int j=0;j<4;j++){
        int row = m0 + wr + mi*16 + ((l>>4)<<2) + j;
        int col = n0 + wc + ni*16 + fr;
        C[(size_t)row*4096 + col] = f2b(acc[mi][ni][j]);
      }
}

// ------- per-step LSTM: W resident in LDS, barrier-free A double-buffer -----
__global__ __launch_bounds__(256) void lstm_step_kernel(
  unsigned short* __restrict__ hbufs, float* __restrict__ cbuf,
  unsigned short* __restrict__ hall, const unsigned short* __restrict__ Gin,
  const unsigned short* __restrict__ WhhF_, const unsigned short* __restrict__ WhhB_,
  const float* __restrict__ bF, const float* __restrict__ bB, int t)
{
  __shared__ __align__(16) unsigned short WL[16*4*64*8];   // 64 KB, [kt][g][lane][8]
  __shared__ __align__(16) unsigned short Ah[2][128*32];   // 16 KB, per-wave-private rows
  const int d = blockIdx.z;
  const int m0 = blockIdx.x<<7;       // s rows
  const int u0 = blockIdx.y<<4;       // hidden units
  const int tin = d ? (7-t) : t;
  const int par = t&1;
  const unsigned short* hprev = hbufs + (size_t)(d*2+par)*262144;
  unsigned short* hnext = hbufs + (size_t)(d*2+(par^1))*262144;
  const unsigned short* W = d ? WhhB_ : WhhF_;
  const float* bias = d ? bB : bF;
  const int tx = threadIdx.x, w = tx>>6, l = tx&63;
  const int fr = l&15, q = l>>4, fk = q<<3;
  // one-time W slice load into LDS (64 gate-rows x 512 K)
  {
    const int row = tx >> 2, qq = tx & 3;
    const int g = row >> 4, ul = row & 15;
    const int grow = (g<<9) + u0 + ul;
    #pragma unroll
    for(int kt=0;kt<16;kt++){
      uint4 v = *(const uint4*)(W + (size_t)grow*512 + kt*32 + qq*8);
      *(uint4*)(WL + ((kt*4+g)*64 + (qq*16+ul))*8) = v;
    }
  }
  __syncthreads();
  f32x4 acc[2][4];
  #pragma unroll
  for(int i=0;i<2;i++)
    #pragma unroll
    for(int j=0;j<4;j++) acc[i][j]=(f32x4)0.f;
  const int r0 = (w<<5) + (l>>2), c0 = (l&3)<<3;
  const unsigned short* hA0 = hprev + (size_t)(m0+r0)*512;
  const unsigned short* hA1 = hprev + (size_t)(m0+r0+16)*512;
  unsigned short* ab0 = Ah[0] + (w<<5)*32;
  unsigned short* ab1 = Ah[1] + (w<<5)*32;
  // prologue: stage k-tile 0 into buf0 (wave-private region -> no barrier needed)
  gll16(hA0 + c0, ab0);
  gll16(hA1 + c0, ab0 + 16*32);
  #pragma unroll
  for(int kt=0;kt<16;kt++){
    const unsigned short* cur = (kt&1) ? ab1 : ab0;
    unsigned short* nxt = (kt&1) ? ab0 : ab1;
    if(kt<15){
      int kc = (kt+1)*32 + c0;
      gll16(hA0 + kc, nxt);
      gll16(hA1 + kc, nxt + 16*32);
      asm volatile("s_waitcnt vmcnt(2)" ::: "memory");   // wait current tile, keep next in flight
    } else {
      asm volatile("s_waitcnt vmcnt(0)" ::: "memory");
    }
    short8 a0 = *(const short8*)(cur + fr*32 + fk);
    short8 a1 = *(const short8*)(cur + (16+fr)*32 + fk);
    short8 bf[4];
    #pragma unroll
    for(int g=0;g<4;g++) bf[g] = *(const short8*)(WL + ((kt*4+g)*64 + l)*8);
    #pragma unroll
    for(int g=0;g<4;g++){
      acc[0][g] = __builtin_amdgcn_mfma_f32_16x16x32_bf16(a0, bf[g], acc[0][g], 0,0,0);
      acc[1][g] = __builtin_amdgcn_mfma_f32_16x16x32_bf16(a1, bf[g], acc[1][g], 0,0,0);
    }
  }
  #pragma unroll
  for(int mi=0;mi<2;mi++)
    #pragma unroll
    for(int j=0;j<4;j++){
      int rs = m0 + w*32 + mi*16 + (q<<2) + j;
      int u  = u0 + fr;
      size_t grow = (size_t)(tin*512 + rs)*4096 + (size_t)d*2048;
      float p0 = acc[mi][0][j] + b2f(Gin[grow +    0 + u]) + bias[   0+u];
      float p1 = acc[mi][1][j] + b2f(Gin[grow +  512 + u]) + bias[ 512+u];
      float p2 = acc[mi][2][j] + b2f(Gin[grow + 1024 + u]) + bias[1024+u];
      float p3 = acc[mi][3][j] + b2f(Gin[grow + 1536 + u]) + bias[1536+u];
      size_t ci = (size_t)d*262144 + (size_t)rs*512 + u;
      float c = sigm(p1)*cbuf[ci] + sigm(p0)*tanh_(p2);
      cbuf[ci] = c;
      float h = sigm(p3)*tanh_(c);
      hnext[(size_t)rs*512+u] = f2b(h);
      hall[(size_t)(tin*512+rs)*1024 + (size_t)d*512 + u] = f2b(h);
    }
}

// ---------------- fc: feats = h_all @ fcW^T + b  -> f32 [4096][64] (padded) --
__global__ __launch_bounds__(256) void fc_kernel(const unsigned short* __restrict__ hA,
    const unsigned short* __restrict__ Wf, const float* __restrict__ fcb,
    float* __restrict__ feats){
  __shared__ __align__(16) unsigned short As[128*40];
  __shared__ __align__(16) unsigned short Bs[64*40];
  const int tx = threadIdx.x, w = tx>>6, l = tx&63;
  const int m0 = blockIdx.x<<7;
  const int srow = tx>>2, scol = (tx&3)<<3;
  const int fr=l&15, fk=(l>>4)<<3;
  f32x4 acc[2][4];
  #pragma unroll
  for(int i=0;i<2;i++)
    #pragma unroll
    for(int j=0;j<4;j++) acc[i][j]=(f32x4)0.f;
  uint4 pa0 = *(const uint4*)(hA + (size_t)(m0+srow)*1024 + scol);
  uint4 pa1 = *(const uint4*)(hA + (size_t)(m0+64+srow)*1024 + scol);
  uint4 pb0 = *(const uint4*)(Wf + (size_t)srow*1024 + scol);
  for(int kt=0; kt<32; ++kt){
    __syncthreads();
    *(uint4*)&As[srow*40+scol] = pa0;
    *(uint4*)&As[(64+srow)*40+scol] = pa1;
    *(uint4*)&Bs[srow*40+scol] = pb0;
    __syncthreads();
    if(kt<31){
      int kc = (kt+1)*32 + scol;
      pa0 = *(const uint4*)(hA + (size_t)(m0+srow)*1024 + kc);
      pa1 = *(const uint4*)(hA + (size_t)(m0+64+srow)*1024 + kc);
      pb0 = *(const uint4*)(Wf + (size_t)srow*1024 + kc);
    }
    short8 af[2], bf[4];
    #pragma unroll
    for(int mi=0;mi<2;mi++) af[mi] = *(const short8*)&As[(w*32+mi*16+fr)*40 + fk];
    #pragma unroll
    for(int ni=0;ni<4;ni++) bf[ni] = *(const short8*)&Bs[(ni*16+fr)*40 + fk];
    #pragma unroll
    for(int mi=0;mi<2;mi++)
      #pragma unroll
      for(int ni=0;ni<4;ni++)
        acc[mi][ni] = __builtin_amdgcn_mfma_f32_16x16x32_bf16(af[mi], bf[ni], acc[mi][ni], 0,0,0);
  }
  #pragma unroll
  for(int mi=0;mi<2;mi++)
    #pragma unroll
    for(int ni=0;ni<4;ni++)
      #pragma unroll
      for(int j=0;j<4;j++){
        int rs = m0 + w*32 + mi*16 + ((l>>4)<<2) + j;
        int n  = ni*16 + fr;
        feats[(size_t)rs*64+n] = acc[mi][ni][j] + (n<50 ? fcb[n] : 0.f);
      }
}

// ---- CRF level 1: product of 16 transition-step matrices per block ---------
__global__ __launch_bounds__(64) void crf_group_kernel(
    const float* __restrict__ feats, const unsigned short* __restrict__ Ebf,
    float* __restrict__ Wout, int* __restrict__ kexp)
{
  __shared__ __align__(16) unsigned short PT[64*72];
  __shared__ float fe[16*64];
  const int g = blockIdx.x, b = blockIdx.y;
  const int l = threadIdx.x;
  const int lj = l & 15, q = l >> 4;
  const float* fb = feats + (size_t)(b*512 + g*16)*64;
  #pragma unroll
  for(int j=0;j<16;j++) fe[j*64 + l] = fb[j*64 + l];
  short8 afE[4][2];
  #pragma unroll
  for(int i=0;i<4;i++)
    #pragma unroll
    for(int h=0;h<2;h++)
      afE[i][h] = *(const short8*)(Ebf + (i*16+lj)*64 + h*32 + q*8);
  {
    uint4 erow[8];
    #pragma unroll
    for(int i=0;i<8;i++) erow[i] = *(const uint4*)(Ebf + l*64 + i*8);
    float ef0 = __expf(fe[l]);
    const unsigned* e32 = (const unsigned*)erow;
    #pragma unroll
    for(int m=0;m<64;m++){
      unsigned short eb = (unsigned short)(e32[m>>1] >> ((m&1)*16));
      PT[m*72 + l] = f2b(b2f(eb) * ef0);
    }
  }
  float sc_lag = 1.f;
  int exprev = 0, kblk = 0;
  #pragma unroll
  for(int k=1;k<16;k++){
    kblk += exprev;
    float ev[4][4];
    #pragma unroll
    for(int i=0;i<4;i++)
      #pragma unroll
      for(int r=0;r<4;r++)
        ev[i][r] = __expf(fe[k*64 + i*16 + q*4 + r]) * sc_lag;
    short8 bfP[4][2];
    #pragma unroll
    for(int j=0;j<4;j++)
      #pragma unroll
      for(int h=0;h<2;h++)
        bfP[j][h] = *(const short8*)&PT[(j*16+lj)*72 + h*32 + q*8];
    f32x4 acc[4][4];
    #pragma unroll
    for(int i=0;i<4;i++)
      #pragma unroll
      for(int j=0;j<4;j++) acc[i][j] = (f32x4)0.f;
    #pragma unroll
    for(int h=0;h<2;h++)
      #pragma unroll
      for(int i=0;i<4;i++)
        #pragma unroll
        for(int j=0;j<4;j++)
          acc[i][j] = __builtin_amdgcn_mfma_f32_16x16x32_bf16(afE[i][h], bfP[j][h], acc[i][j], 0,0,0);
    float mx = 1e-30f;
    float* Wo = Wout + (size_t)(b*32 + g)*4096;
    #pragma unroll
    for(int i=0;i<4;i++)
      #pragma unroll
      for(int j=0;j<4;j++){
        float v0 = acc[i][j][0]*ev[i][0];
        float v1 = acc[i][j][1]*ev[i][1];
        float v2 = acc[i][j][2]*ev[i][2];
        float v3 = acc[i][j][3]*ev[i][3];
        mx = fmaxf(fmaxf(mx, fmaxf(v0,v1)), fmaxf(v2,v3));
        int base = (j*16+lj)*72 + i*16 + q*4;
        *(unsigned*)&PT[base]   = (unsigned)f2b(v0) | ((unsigned)f2b(v1)<<16);
        *(unsigned*)&PT[base+2] = (unsigned)f2b(v2) | ((unsigned)f2b(v3)<<16);
        if(k==15){
          int n = i*16 + q*4, m = j*16 + lj;
          Wo[(size_t)(n+0)*64 + m] = v0;
          Wo[(size_t)(n+1)*64 + m] = v1;
          Wo[(size_t)(n+2)*64 + m] = v2;
          Wo[(size_t)(n+3)*64 + m] = v3;
        }
      }
    #pragma unroll
    for(int off=1; off<64; off<<=1) mx = fmaxf(mx, __shfl_xor(mx, off));
    int ex = ((__builtin_bit_cast(int, mx) >> 23) & 0xff) - 127;
    ex = ex < -120 ? -120 : (ex > 120 ? 120 : ex);
    sc_lag = __builtin_bit_cast(float, (unsigned)((127-ex)<<23));
    exprev = ex;
  }
  if(l==0) kexp[b*32 + g] = kblk;
}

// ---- CRF level 2: sequential over 32 group matrices, pure f32 matvec -------
__global__ __launch_bounds__(64) void crf_seq_kernel(const float* __restrict__ W,
    const int* __restrict__ kexp, const float* __restrict__ trans,
    float* __restrict__ scores){
  __shared__ __align__(16) float sh[64];
  const int b = blockIdx.x, l = threadIdx.x;
  const float* Wb = W + (size_t)b*131072;
  float kl = (l<32) ? (float)kexp[b*32 + l] : 0.f;
  #pragma unroll
  for(int off=32;off;off>>=1) kl += __shfl_down(kl, off);
  float G = (l==48) ? 1.f : 0.f;
  float sc = 1.f, Mrun = 0.f;
  int exprev = 0;
  float4 curA[16], curB[16];
  #pragma unroll
  for(int i=0;i<16;i++) curA[i] = ((const float4*)(Wb + (size_t)l*64))[i];

#define SEQ_STEP(CUR, NXT, GI) {                                            \
    sh[l] = G;                                                              \
    const float* wn = Wb + (size_t)(((GI)+1)&31)*4096 + (size_t)l*64;       \
    _Pragma("unroll")                                                       \
    for(int i=0;i<16;i++) NXT[i] = ((const float4*)wn)[i];                  \
    float4 gq[16];                                                          \
    _Pragma("unroll")                                                       \
    for(int i=0;i<16;i++) gq[i] = ((const float4*)sh)[i];                   \
    float a0=0.f,a1=0.f,a2=0.f,a3=0.f;                                      \
    _Pragma("unroll")                                                       \
    for(int i=0;i<16;i++){                                                  \
      a0 = fmaf(CUR[i].x, gq[i].x, a0);                                     \
      a1 = fmaf(CUR[i].y, gq[i].y, a1);                                     \
      a2 = fmaf(CUR[i].z, gq[i].z, a2);                                     \
      a3 = fmaf(CUR[i].w, gq[i].w, a3);                                     \
    }                                                                       \
    float S = (a0+a1)+(a2+a3);                                              \
    Mrun += (float)exprev;                                                  \
    G = S * sc;                                                             \
    float Sp = __builtin_bit_cast(float, __builtin_amdgcn_readfirstlane(    \
                 __builtin_bit_cast(int, fmaxf(S, 1e-35f))));               \
    int ex = ((__builtin_bit_cast(int, Sp) >> 23) & 0xff) - 127;            \
    ex = ex < -120 ? -120 : (ex > 120 ? 120 : ex);                          \
    sc = __builtin_bit_cast(float, (unsigned)((127-ex)<<23));               \
    exprev = ex;                                                            \
  }

  for(int g=0; g<32; g+=2){
    SEQ_STEP(curA, curB, g)
    SEQ_STEP(curB, curA, g+1)
  }
#undef SEQ_STEP
  float u = (l<50) ? __expf(trans[49*50+l]) : 0.f;
  float val = G * u;
  #pragma unroll
  for(int off=32;off;off>>=1) val += __shfl_down(val, off);
  if(l==0) scores[b] = logf(fmaxf(val,1e-35f)) + (Mrun + kl)*LN2F;
}

// ---------------- gold score + final combine --------------------------------
__global__ __launch_bounds__(256) void final_kernel(const int* __restrict__ Y,
   const float* __restrict__ trans, const float* __restrict__ feats,
   const float* __restrict__ scores, float* __restrict__ out){
  const int tx = threadIdx.x;
  float acc = 0.f;
  for(int i=tx; i<4096; i+=256){
    int s = i & 511;
    int y = Y[i];
    int prev = s ? Y[i-1] : 48;
    acc += trans[y*50+prev] + feats[(size_t)i*64+y];
    if (s==511) acc += trans[49*50+y];
  }
  #pragma unroll
  for(int off=32; off; off>>=1) acc += __shfl_down(acc, off);
  __shared__ float red[4];
  if((tx&63)==0) red[tx>>6] = acc;
  __syncthreads();
  if(tx==0){
    float gold = red[0]+red[1]+red[2]+red[3];
    float fwd = 0.f;
    #pragma unroll
    for(int b=0;b<8;b++) fwd += scores[b];
    out[0] = fwd - gold;
  }
}

extern "C" void kernel_launch(void* const* d_in, const int* in_sizes, int n_in,
                              void* d_out, int out_size, void* d_ws, size_t ws_size,
                              hipStream_t stream) {
  (void)in_sizes; (void)n_in; (void)out_size; (void)ws_size;
  const int*   X     = (const int*)d_in[0];
  const int*   Y     = (const int*)d_in[1];
  const float* h0    = (const float*)d_in[2];
  const float* c0    = (const float*)d_in[3];
  const float* emb   = (const float*)d_in[4];
  const float* WihF  = (const float*)d_in[5];
  const float* WhhFf = (const float*)d_in[6];
  const float* bF    = (const float*)d_in[7];
  const float* WihB  = (const float*)d_in[8];
  const float* WhhBf = (const float*)d_in[9];
  const float* bB    = (const float*)d_in[10];
  const float* fcWf  = (const float*)d_in[11];
  const float* fcb   = (const float*)d_in[12];
  const float* trans = (const float*)d_in[13];
  float* out = (float*)d_out;
  char* ws = (char*)d_ws;

  unsigned short* Abf   = (unsigned short*)(ws + 0);
  unsigned short* Wcat  = (unsigned short*)(ws + 4194304);
  unsigned short* WhhF  = (unsigned short*)(ws + 8388608);
  unsigned short* WhhB  = (unsigned short*)(ws + 10485760);
  unsigned short* Gin   = (unsigned short*)(ws + 12582912);   // 32 MB, reused after lstm
  float*          Wgrp  = (float*)(ws + 12582912);            // overlays Gin after lstm
  int*            kexp  = (int*)(ws + 20971520);
  unsigned short* hbufs = (unsigned short*)(ws + 46137344);
  float*          cbuf  = (float*)(ws + 48234496);
  unsigned short* hall  = (unsigned short*)(ws + 50331648);
  unsigned short* fcW   = (unsigned short*)(ws + 58720256);
  float*          feats = (float*)(ws + 58851328);            // 4096*64 f32 + pad
  unsigned short* Ebf   = (unsigned short*)(ws + 59900160);
  float*          scores= (float*)(ws + 59913472);

  hipLaunchKernelGGL(prep_kernel, dim3(1024), dim3(256), 0, stream,
      X, Y, h0, c0, emb, WihF, WihB, WhhFf, WhhBf, fcWf, trans,
      Abf, Wcat, WhhF, WhhB, hbufs, cbuf, fcW, Ebf, out);
  hipLaunchKernelGGL(gemm1_kernel, dim3(32,32), dim3(256), 0, stream, Abf, Wcat, Gin);
  for(int t=0;t<8;t++)
    hipLaunchKernelGGL(lstm_step_kernel, dim3(4,32,2), dim3(256), 0, stream,
        hbufs, cbuf, hall, Gin, WhhF, WhhB, bF, bB, t);
  hipLaunchKernelGGL(fc_kernel, dim3(32), dim3(256), 0, stream, hall, fcW, fcb, feats);
  hipLaunchKernelGGL(crf_group_kernel, dim3(32,8), dim3(64), 0, stream, feats, Ebf, Wgrp, kexp);
  hipLaunchKernelGGL(crf_seq_kernel, dim3(8), dim3(64), 0, stream, Wgrp, kexp, trans, scores);
  hipLaunchKernelGGL(final_kernel, dim3(1), dim3(256), 0, stream, Y, trans, feats, scores, out);
}

// Round 7
// 189.161 us; speedup vs baseline: 2.3343x; 1.1084x over previous
//
#include <hip/hip_runtime.h>
#include <hip/hip_bf16.h>

typedef __attribute__((ext_vector_type(4))) float f32x4;
typedef __attribute__((ext_vector_type(8))) short short8;

#define LN2F 0.69314718055994531f

__device__ __forceinline__ unsigned short f2b(float x){
  union{float f;unsigned u;}v; v.f=x;
  unsigned r = v.u + 0x7fffu + ((v.u>>16)&1u);
  return (unsigned short)(r>>16);
}
__device__ __forceinline__ float b2f(unsigned short h){
  union{unsigned u;float f;}v; v.u = ((unsigned)h)<<16; return v.f;
}
__device__ __forceinline__ float sigm(float x){ return 1.f/(1.f+__expf(-x)); }
__device__ __forceinline__ float tanh_(float x){ float t=__expf(2.f*x); return 1.f - 2.f/(t+1.f); }

// async global->LDS, 16B per lane; LDS dest = wave-uniform base + lane*16
__device__ __forceinline__ void gll16(const void* g, void* l){
  __builtin_amdgcn_global_load_lds((const __attribute__((address_space(1))) void*)g,
                                   (__attribute__((address_space(3))) void*)l, 16, 0, 0);
}

// ---------------- prep: gathers + f32->bf16 conversions + E table + Y out ----
__global__ __launch_bounds__(256) void prep_kernel(
  const int* __restrict__ X, const int* __restrict__ Y,
  const float* __restrict__ h0, const float* __restrict__ c0,
  const float* __restrict__ emb,
  const float* __restrict__ WihF, const float* __restrict__ WihB,
  const float* __restrict__ WhhFf, const float* __restrict__ WhhBf,
  const float* __restrict__ fcWf, const float* __restrict__ trans,
  unsigned short* __restrict__ Abf, unsigned short* __restrict__ Wcat,
  unsigned short* __restrict__ WhhF, unsigned short* __restrict__ WhhB,
  unsigned short* __restrict__ hbufs, float* __restrict__ cbuf,
  unsigned short* __restrict__ fcW, unsigned short* __restrict__ Ebf,
  float* __restrict__ out)
{
  const int tid = blockIdx.x*256 + threadIdx.x;
  const int nth = gridDim.x*256;
  if(tid==0) out[0] = 0.f;              // accumulator for fused score (replay-safe)
  for(int i=tid;i<524288;i+=nth){
    int r = i>>7, q = i&127;
    float4 v = ((const float4*)(emb + (size_t)X[r]*512))[q];
    ushort4 o; o.x=f2b(v.x); o.y=f2b(v.y); o.z=f2b(v.z); o.w=f2b(v.w);
    ((ushort4*)Abf)[i] = o;
  }
  for(int i=tid;i<524288;i+=nth){
    int r = i>>7, q = i&127;
    const float* src = (r<2048) ? (WihF + (size_t)r*512) : (WihB + (size_t)(r-2048)*512);
    float4 v = ((const float4*)src)[q];
    ushort4 o; o.x=f2b(v.x); o.y=f2b(v.y); o.z=f2b(v.z); o.w=f2b(v.w);
    ((ushort4*)Wcat)[i] = o;
  }
  for(int i=tid;i<262144;i+=nth){
    float4 v = ((const float4*)WhhFf)[i];
    ushort4 o; o.x=f2b(v.x); o.y=f2b(v.y); o.z=f2b(v.z); o.w=f2b(v.w);
    ((ushort4*)WhhF)[i] = o;
  }
  for(int i=tid;i<262144;i+=nth){
    float4 v = ((const float4*)WhhBf)[i];
    ushort4 o; o.x=f2b(v.x); o.y=f2b(v.y); o.z=f2b(v.z); o.w=f2b(v.w);
    ((ushort4*)WhhB)[i] = o;
  }
  for(int i=tid;i<131072;i+=nth){
    int d = i>>16, rest = i&65535;
    float4 v = ((const float4*)h0)[i];
    ushort4 o; o.x=f2b(v.x); o.y=f2b(v.y); o.z=f2b(v.z); o.w=f2b(v.w);
    ((ushort4*)hbufs)[(size_t)(d*2)*65536 + rest] = o;
  }
  for(int i=tid;i<131072;i+=nth) ((float4*)cbuf)[i] = ((const float4*)c0)[i];
  for(int i=tid;i<16384;i+=nth){
    int n = i>>8, q = i&255;
    float4 v;
    if (n<50) v = ((const float4*)(fcWf + (size_t)n*1024))[q];
    else { v.x=0.f; v.y=0.f; v.z=0.f; v.w=0.f; }
    ushort4 o; o.x=f2b(v.x); o.y=f2b(v.y); o.z=f2b(v.z); o.w=f2b(v.w);
    ((ushort4*)fcW)[i] = o;
  }
  // Ebf[n][p] = exp(trans[n][p]) bf16, padded [64][64]
  for(int i=tid;i<4096;i+=nth){
    int n = i>>6, p = i&63;
    float v = (n<50 && p<50) ? __expf(trans[n*50+p]) : 0.f;
    Ebf[i] = f2b(v);
  }
  for(int i=tid;i<4096;i+=nth) out[1+i] = (float)Y[i];
}

// ---------------- GEMM1: Gin = A @ Wcat^T, 2-phase pipelined staging --------
__global__ __launch_bounds__(256) void gemm1_kernel(const unsigned short* __restrict__ A,
                                                    const unsigned short* __restrict__ B,
                                                    unsigned short* __restrict__ C){
  __shared__ __align__(16) unsigned short As[2][128*32];
  __shared__ __align__(16) unsigned short Bs[2][128*32];
  const int t = threadIdx.x, w = t>>6, l = t&63;
  const int m0 = blockIdx.x<<7, n0 = blockIdx.y<<7;
  const int wr = (w>>1)<<6, wc = (w&1)<<6;
  const int fr = l&15, fk = (l>>4)<<3;
  f32x4 acc[4][4];
  #pragma unroll
  for(int i=0;i<4;i++)
    #pragma unroll
    for(int j=0;j<4;j++) acc[i][j]=(f32x4)0.f;
  const unsigned short* Ab = A + (size_t)m0*512;
  const unsigned short* Bb = B + (size_t)n0*512;
  const int r0 = (w<<5) + (l>>2);       // wave w stages rows w*32..w*32+31 (2 segs)
  const int c0 = (l&3)<<3;
  const int wo = (w<<5)*32;
  // prologue: tile 0
  gll16(Ab + (size_t)r0*512 + c0,      As[0] + wo);
  gll16(Ab + (size_t)(r0+16)*512 + c0, As[0] + wo + 16*32);
  gll16(Bb + (size_t)r0*512 + c0,      Bs[0] + wo);
  gll16(Bb + (size_t)(r0+16)*512 + c0, Bs[0] + wo + 16*32);
  asm volatile("s_waitcnt vmcnt(0)" ::: "memory");
  __syncthreads();
  int cur = 0;
  for(int kt=0; kt<16; ++kt){
    if(kt<15){                                    // issue next tile BEFORE compute
      const int kc = ((kt+1)<<5) + c0;
      gll16(Ab + (size_t)r0*512 + kc,      As[cur^1] + wo);
      gll16(Ab + (size_t)(r0+16)*512 + kc, As[cur^1] + wo + 16*32);
      gll16(Bb + (size_t)r0*512 + kc,      Bs[cur^1] + wo);
      gll16(Bb + (size_t)(r0+16)*512 + kc, Bs[cur^1] + wo + 16*32);
    }
    short8 af[4], bf[4];
    #pragma unroll
    for(int mi=0;mi<4;mi++) af[mi] = *(const short8*)&As[cur][(wr+mi*16+fr)*32 + fk];
    #pragma unroll
    for(int ni=0;ni<4;ni++) bf[ni] = *(const short8*)&Bs[cur][(wc+ni*16+fr)*32 + fk];
    #pragma unroll
    for(int mi=0;mi<4;mi++)
      #pragma unroll
      for(int ni=0;ni<4;ni++)
        acc[mi][ni] = __builtin_amdgcn_mfma_f32_16x16x32_bf16(af[mi], bf[ni], acc[mi][ni], 0,0,0);
    asm volatile("s_waitcnt vmcnt(0)" ::: "memory");
    __syncthreads();
    cur ^= 1;
  }
  #pragma unroll
  for(int mi=0;mi<4;mi++)
    #pragma unroll
    for(int ni=0;ni<4;ni++)
      #pragma unroll
      for(int j=0;j<4;j++){
        int row = m0 + wr + mi*16 + ((l>>4)<<2) + j;
        int col = n0 + wc + ni*16 + fr;
        C[(size_t)row*4096 + col] = f2b(acc[mi][ni][j]);
      }
}

// ------- per-step LSTM: W in LDS, barrier-free 4-deep A ring ----------------
__global__ __launch_bounds__(256) void lstm_step_kernel(
  unsigned short* __restrict__ hbufs, float* __restrict__ cbuf,
  unsigned short* __restrict__ hall, const unsigned short* __restrict__ Gin,
  const unsigned short* __restrict__ WhhF_, const unsigned short* __restrict__ WhhB_,
  const float* __restrict__ bF, const float* __restrict__ bB, int t)
{
  __shared__ __align__(16) unsigned short WL[16*4*64*8];   // 64 KB, [kt][g][lane][8]
  __shared__ __align__(16) unsigned short Ab4[4][128*32];  // 32 KB ring, wave-private rows
  const int d = blockIdx.z;
  const int m0 = blockIdx.x<<7;       // s rows
  const int u0 = blockIdx.y<<4;       // hidden units
  const int tin = d ? (7-t) : t;
  const int par = t&1;
  const unsigned short* hprev = hbufs + (size_t)(d*2+par)*262144;
  unsigned short* hnext = hbufs + (size_t)(d*2+(par^1))*262144;
  const unsigned short* W = d ? WhhB_ : WhhF_;
  const float* bias = d ? bB : bF;
  const int tx = threadIdx.x, w = tx>>6, l = tx&63;
  const int fr = l&15, q = l>>4, fk = q<<3;
  // one-time W slice load into LDS (64 gate-rows x 512 K)
  {
    const int row = tx >> 2, qq = tx & 3;
    const int g = row >> 4, ul = row & 15;
    const int grow = (g<<9) + u0 + ul;
    #pragma unroll
    for(int kt=0;kt<16;kt++){
      uint4 v = *(const uint4*)(W + (size_t)grow*512 + kt*32 + qq*8);
      *(uint4*)(WL + ((kt*4+g)*64 + (qq*16+ul))*8) = v;
    }
  }
  __syncthreads();
  f32x4 acc[2][4];
  #pragma unroll
  for(int i=0;i<2;i++)
    #pragma unroll
    for(int j=0;j<4;j++) acc[i][j]=(f32x4)0.f;
  const int r0 = (w<<5) + (l>>2), c0 = (l&3)<<3;
  const unsigned short* hA0 = hprev + (size_t)(m0+r0)*512;
  const unsigned short* hA1 = hprev + (size_t)(m0+r0+16)*512;
#define ABUF(i) (Ab4[(i)] + ((w<<5)*32))
  // prologue: stage tiles 0..3 (wave-private dest -> no barriers needed)
  gll16(hA0 + 0*32 + c0, ABUF(0)); gll16(hA1 + 0*32 + c0, ABUF(0)+16*32);
  gll16(hA0 + 1*32 + c0, ABUF(1)); gll16(hA1 + 1*32 + c0, ABUF(1)+16*32);
  gll16(hA0 + 2*32 + c0, ABUF(2)); gll16(hA1 + 2*32 + c0, ABUF(2)+16*32);
  gll16(hA0 + 3*32 + c0, ABUF(3)); gll16(hA1 + 3*32 + c0, ABUF(3)+16*32);
#define LSTEP(KT, VM) {                                                       \
    if((KT)+4 < 16){                                                          \
      const int kc_ = ((KT)+4)*32 + c0;                                       \
      gll16(hA0 + kc_, ABUF(((KT)+4)&3));                                     \
      gll16(hA1 + kc_, ABUF(((KT)+4)&3)+16*32);                               \
    }                                                                         \
    asm volatile("s_waitcnt vmcnt(" VM ")" ::: "memory");                     \
    const unsigned short* cur_ = ABUF((KT)&3);                                \
    short8 a0_ = *(const short8*)(cur_ + fr*32 + fk);                         \
    short8 a1_ = *(const short8*)(cur_ + (16+fr)*32 + fk);                    \
    short8 bv_[4];                                                            \
    _Pragma("unroll")                                                         \
    for(int g=0;g<4;g++) bv_[g] = *(const short8*)(WL + (((KT)*4+g)*64 + l)*8);\
    _Pragma("unroll")                                                         \
    for(int g=0;g<4;g++){                                                     \
      acc[0][g] = __builtin_amdgcn_mfma_f32_16x16x32_bf16(a0_, bv_[g], acc[0][g], 0,0,0); \
      acc[1][g] = __builtin_amdgcn_mfma_f32_16x16x32_bf16(a1_, bv_[g], acc[1][g], 0,0,0); \
    }                                                                         \
  }
  LSTEP(0,"8")  LSTEP(1,"8")  LSTEP(2,"8")  LSTEP(3,"8")
  LSTEP(4,"8")  LSTEP(5,"8")  LSTEP(6,"8")  LSTEP(7,"8")
  LSTEP(8,"8")  LSTEP(9,"8")  LSTEP(10,"8") LSTEP(11,"8")
  LSTEP(12,"6") LSTEP(13,"4") LSTEP(14,"2") LSTEP(15,"0")
#undef LSTEP
#undef ABUF
  #pragma unroll
  for(int mi=0;mi<2;mi++)
    #pragma unroll
    for(int j=0;j<4;j++){
      int rs = m0 + w*32 + mi*16 + (q<<2) + j;
      int u  = u0 + fr;
      size_t grow = (size_t)(tin*512 + rs)*4096 + (size_t)d*2048;
      float p0 = acc[mi][0][j] + b2f(Gin[grow +    0 + u]) + bias[   0+u];
      float p1 = acc[mi][1][j] + b2f(Gin[grow +  512 + u]) + bias[ 512+u];
      float p2 = acc[mi][2][j] + b2f(Gin[grow + 1024 + u]) + bias[1024+u];
      float p3 = acc[mi][3][j] + b2f(Gin[grow + 1536 + u]) + bias[1536+u];
      size_t ci = (size_t)d*262144 + (size_t)rs*512 + u;
      float c = sigm(p1)*cbuf[ci] + sigm(p0)*tanh_(p2);
      cbuf[ci] = c;
      float h = sigm(p3)*tanh_(c);
      hnext[(size_t)rs*512+u] = f2b(h);
      hall[(size_t)(tin*512+rs)*1024 + (size_t)d*512 + u] = f2b(h);
    }
}

// ---------------- fc: feats = h_all @ fcW^T + b  -> f32 [4096][64] (padded) --
__global__ __launch_bounds__(256) void fc_kernel(const unsigned short* __restrict__ hA,
    const unsigned short* __restrict__ Wf, const float* __restrict__ fcb,
    float* __restrict__ feats){
  __shared__ __align__(16) unsigned short As[128*40];
  __shared__ __align__(16) unsigned short Bs[64*40];
  const int tx = threadIdx.x, w = tx>>6, l = tx&63;
  const int m0 = blockIdx.x<<7;
  const int srow = tx>>2, scol = (tx&3)<<3;
  const int fr=l&15, fk=(l>>4)<<3;
  f32x4 acc[2][4];
  #pragma unroll
  for(int i=0;i<2;i++)
    #pragma unroll
    for(int j=0;j<4;j++) acc[i][j]=(f32x4)0.f;
  uint4 pa0 = *(const uint4*)(hA + (size_t)(m0+srow)*1024 + scol);
  uint4 pa1 = *(const uint4*)(hA + (size_t)(m0+64+srow)*1024 + scol);
  uint4 pb0 = *(const uint4*)(Wf + (size_t)srow*1024 + scol);
  for(int kt=0; kt<32; ++kt){
    __syncthreads();
    *(uint4*)&As[srow*40+scol] = pa0;
    *(uint4*)&As[(64+srow)*40+scol] = pa1;
    *(uint4*)&Bs[srow*40+scol] = pb0;
    __syncthreads();
    if(kt<31){
      int kc = (kt+1)*32 + scol;
      pa0 = *(const uint4*)(hA + (size_t)(m0+srow)*1024 + kc);
      pa1 = *(const uint4*)(hA + (size_t)(m0+64+srow)*1024 + kc);
      pb0 = *(const uint4*)(Wf + (size_t)srow*1024 + kc);
    }
    short8 af[2], bf[4];
    #pragma unroll
    for(int mi=0;mi<2;mi++) af[mi] = *(const short8*)&As[(w*32+mi*16+fr)*40 + fk];
    #pragma unroll
    for(int ni=0;ni<4;ni++) bf[ni] = *(const short8*)&Bs[(ni*16+fr)*40 + fk];
    #pragma unroll
    for(int mi=0;mi<2;mi++)
      #pragma unroll
      for(int ni=0;ni<4;ni++)
        acc[mi][ni] = __builtin_amdgcn_mfma_f32_16x16x32_bf16(af[mi], bf[ni], acc[mi][ni], 0,0,0);
  }
  #pragma unroll
  for(int mi=0;mi<2;mi++)
    #pragma unroll
    for(int ni=0;ni<4;ni++)
      #pragma unroll
      for(int j=0;j<4;j++){
        int rs = m0 + w*32 + mi*16 + ((l>>4)<<2) + j;
        int n  = ni*16 + fr;
        feats[(size_t)rs*64+n] = acc[mi][ni][j] + (n<50 ? fcb[n] : 0.f);
      }
}

// ---- CRF level 1: product of 16 transition-step matrices per block ---------
__global__ __launch_bounds__(64) void crf_group_kernel(
    const float* __restrict__ feats, const unsigned short* __restrict__ Ebf,
    float* __restrict__ Wout, int* __restrict__ kexp)
{
  __shared__ __align__(16) unsigned short PT[64*72];
  __shared__ float fe[16*64];
  const int g = blockIdx.x, b = blockIdx.y;
  const int l = threadIdx.x;
  const int lj = l & 15, q = l >> 4;
  const float* fb = feats + (size_t)(b*512 + g*16)*64;
  #pragma unroll
  for(int j=0;j<16;j++) fe[j*64 + l] = fb[j*64 + l];
  short8 afE[4][2];
  #pragma unroll
  for(int i=0;i<4;i++)
    #pragma unroll
    for(int h=0;h<2;h++)
      afE[i][h] = *(const short8*)(Ebf + (i*16+lj)*64 + h*32 + q*8);
  {
    uint4 erow[8];
    #pragma unroll
    for(int i=0;i<8;i++) erow[i] = *(const uint4*)(Ebf + l*64 + i*8);
    float ef0 = __expf(fe[l]);
    const unsigned* e32 = (const unsigned*)erow;
    #pragma unroll
    for(int m=0;m<64;m++){
      unsigned short eb = (unsigned short)(e32[m>>1] >> ((m&1)*16));
      PT[m*72 + l] = f2b(b2f(eb) * ef0);
    }
  }
  float sc_lag = 1.f;
  int exprev = 0, kblk = 0;
  #pragma unroll
  for(int k=1;k<16;k++){
    kblk += exprev;
    float ev[4][4];
    #pragma unroll
    for(int i=0;i<4;i++)
      #pragma unroll
      for(int r=0;r<4;r++)
        ev[i][r] = __expf(fe[k*64 + i*16 + q*4 + r]) * sc_lag;
    short8 bfP[4][2];
    #pragma unroll
    for(int j=0;j<4;j++)
      #pragma unroll
      for(int h=0;h<2;h++)
        bfP[j][h] = *(const short8*)&PT[(j*16+lj)*72 + h*32 + q*8];
    f32x4 acc[4][4];
    #pragma unroll
    for(int i=0;i<4;i++)
      #pragma unroll
      for(int j=0;j<4;j++) acc[i][j] = (f32x4)0.f;
    #pragma unroll
    for(int h=0;h<2;h++)
      #pragma unroll
      for(int i=0;i<4;i++)
        #pragma unroll
        for(int j=0;j<4;j++)
          acc[i][j] = __builtin_amdgcn_mfma_f32_16x16x32_bf16(afE[i][h], bfP[j][h], acc[i][j], 0,0,0);
    float mx = 1e-30f;
    float* Wo = Wout + (size_t)(b*32 + g)*4096;
    #pragma unroll
    for(int i=0;i<4;i++)
      #pragma unroll
      for(int j=0;j<4;j++){
        float v0 = acc[i][j][0]*ev[i][0];
        float v1 = acc[i][j][1]*ev[i][1];
        float v2 = acc[i][j][2]*ev[i][2];
        float v3 = acc[i][j][3]*ev[i][3];
        mx = fmaxf(fmaxf(mx, fmaxf(v0,v1)), fmaxf(v2,v3));
        int base = (j*16+lj)*72 + i*16 + q*4;
        *(unsigned*)&PT[base]   = (unsigned)f2b(v0) | ((unsigned)f2b(v1)<<16);
        *(unsigned*)&PT[base+2] = (unsigned)f2b(v2) | ((unsigned)f2b(v3)<<16);
        if(k==15){
          int n = i*16 + q*4, m = j*16 + lj;
          Wo[(size_t)(n+0)*64 + m] = v0;
          Wo[(size_t)(n+1)*64 + m] = v1;
          Wo[(size_t)(n+2)*64 + m] = v2;
          Wo[(size_t)(n+3)*64 + m] = v3;
        }
      }
    #pragma unroll
    for(int off=1; off<64; off<<=1) mx = fmaxf(mx, __shfl_xor(mx, off));
    int ex = ((__builtin_bit_cast(int, mx) >> 23) & 0xff) - 127;
    ex = ex < -120 ? -120 : (ex > 120 ? 120 : ex);
    sc_lag = __builtin_bit_cast(float, (unsigned)((127-ex)<<23));
    exprev = ex;
  }
  if(l==0) kexp[b*32 + g] = kblk;
}

// ---- CRF level 2 + fused gold/final: blocks 0-7 chains, block 8 gold -------
__global__ __launch_bounds__(256) void crf_seq_kernel(const float* __restrict__ W,
    const int* __restrict__ kexp, const float* __restrict__ trans,
    const float* __restrict__ feats, const int* __restrict__ Y,
    float* __restrict__ out){
  const int b = blockIdx.x;
  if(b < 8){
    if(threadIdx.x >= 64) return;
    __shared__ __align__(16) float sh[64];
    const int l = threadIdx.x;
    const float* Wb = W + (size_t)b*131072;
    float kl = (l<32) ? (float)kexp[b*32 + l] : 0.f;
    #pragma unroll
    for(int off=32;off;off>>=1) kl += __shfl_down(kl, off);
    float G = (l==48) ? 1.f : 0.f;
    float sc = 1.f, Mrun = 0.f;
    int exprev = 0;
    float4 curA[16], curB[16];
    #pragma unroll
    for(int i=0;i<16;i++) curA[i] = ((const float4*)(Wb + (size_t)l*64))[i];

#define SEQ_STEP(CUR, NXT, GI) {                                            \
    sh[l] = G;                                                              \
    const float* wn = Wb + (size_t)(((GI)+1)&31)*4096 + (size_t)l*64;       \
    _Pragma("unroll")                                                       \
    for(int i=0;i<16;i++) NXT[i] = ((const float4*)wn)[i];                  \
    float4 gq[16];                                                          \
    _Pragma("unroll")                                                       \
    for(int i=0;i<16;i++) gq[i] = ((const float4*)sh)[i];                   \
    float a0=0.f,a1=0.f,a2=0.f,a3=0.f;                                      \
    _Pragma("unroll")                                                       \
    for(int i=0;i<16;i++){                                                  \
      a0 = fmaf(CUR[i].x, gq[i].x, a0);                                     \
      a1 = fmaf(CUR[i].y, gq[i].y, a1);                                     \
      a2 = fmaf(CUR[i].z, gq[i].z, a2);                                     \
      a3 = fmaf(CUR[i].w, gq[i].w, a3);                                     \
    }                                                                       \
    float S = (a0+a1)+(a2+a3);                                              \
    Mrun += (float)exprev;                                                  \
    G = S * sc;                                                             \
    float Sp = __builtin_bit_cast(float, __builtin_amdgcn_readfirstlane(    \
                 __builtin_bit_cast(int, fmaxf(S, 1e-35f))));               \
    int ex = ((__builtin_bit_cast(int, Sp) >> 23) & 0xff) - 127;            \
    ex = ex < -120 ? -120 : (ex > 120 ? 120 : ex);                          \
    sc = __builtin_bit_cast(float, (unsigned)((127-ex)<<23));               \
    exprev = ex;                                                            \
  }

    for(int g=0; g<32; g+=2){
      SEQ_STEP(curA, curB, g)
      SEQ_STEP(curB, curA, g+1)
    }
#undef SEQ_STEP
    float u = (l<50) ? __expf(trans[49*50+l]) : 0.f;
    float val = G * u;
    #pragma unroll
    for(int off=32;off;off>>=1) val += __shfl_down(val, off);
    if(l==0) atomicAdd(out, logf(fmaxf(val,1e-35f)) + (Mrun + kl)*LN2F);
  } else {
    // gold path score (negated into the accumulator)
    const int tx = threadIdx.x;
    float acc = 0.f;
    for(int i=tx; i<4096; i+=256){
      int s = i & 511;
      int y = Y[i];
      int prev = s ? Y[i-1] : 48;
      acc += trans[y*50+prev] + feats[(size_t)i*64+y];
      if (s==511) acc += trans[49*50+y];
    }
    #pragma unroll
    for(int off=32; off; off>>=1) acc += __shfl_down(acc, off);
    __shared__ float red[4];
    if((tx&63)==0) red[tx>>6] = acc;
    __syncthreads();
    if(tx==0) atomicAdd(out, -(red[0]+red[1]+red[2]+red[3]));
  }
}

extern "C" void kernel_launch(void* const* d_in, const int* in_sizes, int n_in,
                              void* d_out, int out_size, void* d_ws, size_t ws_size,
                              hipStream_t stream) {
  (void)in_sizes; (void)n_in; (void)out_size; (void)ws_size;
  const int*   X     = (const int*)d_in[0];
  const int*   Y     = (const int*)d_in[1];
  const float* h0    = (const float*)d_in[2];
  const float* c0    = (const float*)d_in[3];
  const float* emb   = (const float*)d_in[4];
  const float* WihF  = (const float*)d_in[5];
  const float* WhhFf = (const float*)d_in[6];
  const float* bF    = (const float*)d_in[7];
  const float* WihB  = (const float*)d_in[8];
  const float* WhhBf = (const float*)d_in[9];
  const float* bB    = (const float*)d_in[10];
  const float* fcWf  = (const float*)d_in[11];
  const float* fcb   = (const float*)d_in[12];
  const float* trans = (const float*)d_in[13];
  float* out = (float*)d_out;
  char* ws = (char*)d_ws;

  unsigned short* Abf   = (unsigned short*)(ws + 0);
  unsigned short* Wcat  = (unsigned short*)(ws + 4194304);
  unsigned short* WhhF  = (unsigned short*)(ws + 8388608);
  unsigned short* WhhB  = (unsigned short*)(ws + 10485760);
  unsigned short* Gin   = (unsigned short*)(ws + 12582912);   // 32 MB, reused after lstm
  float*          Wgrp  = (float*)(ws + 12582912);            // overlays Gin after lstm
  int*            kexp  = (int*)(ws + 20971520);
  unsigned short* hbufs = (unsigned short*)(ws + 46137344);
  float*          cbuf  = (float*)(ws + 48234496);
  unsigned short* hall  = (unsigned short*)(ws + 50331648);
  unsigned short* fcW   = (unsigned short*)(ws + 58720256);
  float*          feats = (float*)(ws + 58851328);            // 4096*64 f32 + pad
  unsigned short* Ebf   = (unsigned short*)(ws + 59900160);

  hipLaunchKernelGGL(prep_kernel, dim3(1024), dim3(256), 0, stream,
      X, Y, h0, c0, emb, WihF, WihB, WhhFf, WhhBf, fcWf, trans,
      Abf, Wcat, WhhF, WhhB, hbufs, cbuf, fcW, Ebf, out);
  hipLaunchKernelGGL(gemm1_kernel, dim3(32,32), dim3(256), 0, stream, Abf, Wcat, Gin);
  for(int t=0;t<8;t++)
    hipLaunchKernelGGL(lstm_step_kernel, dim3(4,32,2), dim3(256), 0, stream,
        hbufs, cbuf, hall, Gin, WhhF, WhhB, bF, bB, t);
  hipLaunchKernelGGL(fc_kernel, dim3(32), dim3(256), 0, stream, hall, fcW, fcb, feats);
  hipLaunchKernelGGL(crf_group_kernel, dim3(32,8), dim3(64), 0, stream, feats, Ebf, Wgrp, kexp);
  hipLaunchKernelGGL(crf_seq_kernel, dim3(9), dim3(256), 0, stream, Wgrp, kexp, trans, feats, Y, out);
}